// Round 14
// baseline (1537.789 us; speedup 1.0000x reference)
//
#include <hip/hip_runtime.h>
#include <hip/hip_fp16.h>

#define NN 100000
#define NE 1600000
#define SHIFT 7
#define NBUCK 782   // ceil(NN / 128) dst-buckets, 128 nodes each
#define P1B   782   // edge-slice blocks
#define EPB   2047  // ceil(NE / P1B)

typedef _Float16 f16x8 __attribute__((ext_vector_type(8)));
typedef float f32x4 __attribute__((ext_vector_type(4)));
union H8U4 { f16x8 h; uint4 u; };

// 256-thread inclusive Hillis-Steele scan in LDS; returns inclusive value for this thread.
__device__ __forceinline__ int scan256(int* s, int t, int v) {
    s[t] = v;
    __syncthreads();
    for (int off = 1; off < 256; off <<= 1) {
        int add = (t >= off) ? s[t - off] : 0;
        __syncthreads();
        s[t] += add;
        __syncthreads();
    }
    return s[t];
}

// ---------------- fused: f16 convert + weight prep + LDS histogram + bin totals ----------------
__global__ __launch_bounds__(256) void k_hist(
    const float4* __restrict__ x4, ushort4* __restrict__ xh4,
    const float* __restrict__ Wl1, const float* __restrict__ Wr1, unsigned short* __restrict__ wt1,
    const float* __restrict__ Wl2, const float* __restrict__ Wr2, unsigned short* __restrict__ wt2,
    const int* __restrict__ dst, int* __restrict__ hist, int* __restrict__ bin_total)
{
    __shared__ int h[NBUCK];
    int t = threadIdx.x, blk = blockIdx.x;

    const int n4 = NN * 16;
    const int per = (n4 + P1B - 1) / P1B;  // 2047
    int cb = blk * per, ce = min(cb + per, n4);
    for (int i = cb + t; i < ce; i += 256) {
        float4 f = x4[i];
        _Float16 a = (_Float16)f.x, b = (_Float16)f.y, c = (_Float16)f.z, d = (_Float16)f.w;
        ushort4 u;
        u.x = *(unsigned short*)&a; u.y = *(unsigned short*)&b;
        u.z = *(unsigned short*)&c; u.w = *(unsigned short*)&d;
        xh4[i] = u;
    }
    if (blk < 64) {  // blocks 0..31 -> wt1, 32..63 -> wt2
        int idx = (blk & 31) * 256 + t;  // 0..8191
        const float* Wl = (blk < 32) ? Wl1 : Wl2;
        const float* Wr = (blk < 32) ? Wr1 : Wr2;
        unsigned short* wt = (blk < 32) ? wt1 : wt2;
        int n = idx >> 7, k = idx & 127;
        float v = (k < 64) ? Wl[k * 64 + n] : Wr[(k - 64) * 64 + n];
        _Float16 hv = (_Float16)v;
        wt[idx] = *(unsigned short*)&hv;
    }

    for (int i = t; i < NBUCK; i += 256) h[i] = 0;
    __syncthreads();
    int eb = blk * EPB, ee = min(eb + EPB, NE);
    for (int e = eb + t; e < ee; e += 256) atomicAdd(&h[dst[e] >> SHIFT], 1);
    __syncthreads();
    for (int i = t; i < NBUCK; i += 256) {
        int v = h[i];
        hist[(size_t)i * P1B + blk] = v;
        if (v) atomicAdd(&bin_total[i], v);  // fire-and-forget
    }
}

// ---------------- cursor bases: block b computes bucket_start[b] locally, then scans hist row b ----------------
__global__ __launch_bounds__(256) void k_cursor(int* __restrict__ hist, const int* __restrict__ bin_total,
                                                int* __restrict__ bucket_start) {
    __shared__ int sS[256];
    int b = blockIdx.x, t = threadIdx.x;

    // base = sum of bin_total[0..b-1]
    int v = 0;
    for (int i = t; i < b; i += 256) v += bin_total[i];
    sS[t] = v;
    __syncthreads();
    for (int s = 128; s > 0; s >>= 1) {
        if (t < s) sS[t] += sS[t + s];
        __syncthreads();
    }
    int base = sS[0];
    __syncthreads();
    if (t == 0) bucket_start[b] = base;
    if (b == 0 && t == 0) bucket_start[NBUCK] = NE;

    // exclusive scan of hist row b (length P1B=782, 4 chunks of 256), in place, +base
    int carry = 0;
#pragma unroll
    for (int c = 0; c < 4; c++) {
        int idx = c * 256 + t;
        int hv = (idx < P1B) ? hist[(size_t)b * P1B + idx] : 0;
        int incl = scan256(sS, t, hv);
        if (idx < P1B) hist[(size_t)b * P1B + idx] = base + carry + incl - hv;
        __syncthreads();
        carry += sS[255];
        __syncthreads();
    }
}

// ---------------- scatter packed (src | (dst&127)<<17) into bucket order ----------------
__global__ __launch_bounds__(256) void k_scatter(const int* __restrict__ src, const int* __restrict__ dst,
                                                 const int* __restrict__ hist, unsigned int* __restrict__ pairs) {
    __shared__ int cur[NBUCK];
    int t = threadIdx.x, blk = blockIdx.x;
    for (int i = t; i < NBUCK; i += 256) cur[i] = hist[(size_t)i * P1B + blk];
    __syncthreads();
    int eb = blk * EPB, ee = min(eb + EPB, NE);
    for (int e = eb + t; e < ee; e += 256) {
        int d = dst[e];
        int pos = atomicAdd(&cur[d >> SHIFT], 1);
        pairs[pos] = (unsigned int)src[e] | ((unsigned int)(d & 127) << 17);
    }
}

// ---------------- bucket-parallel gather-mean: block = bucket, LDS fp32 accumulation ----------------
// 512 threads = 8 waves. Lane: chunk c=l&7 (16B f16x8), edge-slot g=l>>3. Wave w owns edge
// groups at beg+w*8, stride 64. Main loop prefetches 4 groups (4 gathers in flight).
__global__ __launch_bounds__(512) void k_bucket_agg(const uint4* __restrict__ featq,
                                                    const unsigned int* __restrict__ pairs,
                                                    const int* __restrict__ bucket_start,
                                                    uint4* __restrict__ outq) {
    __shared__ float acc[128 * 65];  // +1 pad: LDS atomic bank spread
    __shared__ int cnt[128];
    int b = blockIdx.x, t = threadIdx.x;

    for (int i = t; i < 128 * 65 / 4; i += 512) ((float4*)acc)[i] = (float4){0.f, 0.f, 0.f, 0.f};
    if (t < 128) cnt[t] = 0;
    __syncthreads();

    int beg = bucket_start[b], end = bucket_start[b + 1];
    int lane = t & 63, wave = t >> 6;
    int c = lane & 7, g = lane >> 3;

    int e = beg + wave * 8;
    // main loop: 4 groups per iter (wave stride 64 edges between groups)
    for (; e + 200 <= end; e += 256) {
        unsigned int pr0 = pairs[e + g];
        unsigned int pr1 = pairs[e + 64 + g];
        unsigned int pr2 = pairs[e + 128 + g];
        unsigned int pr3 = pairs[e + 192 + g];
        H8U4 q0, q1, q2, q3;
        q0.u = featq[(size_t)(pr0 & 0x1FFFFu) * 8 + c];
        q1.u = featq[(size_t)(pr1 & 0x1FFFFu) * 8 + c];
        q2.u = featq[(size_t)(pr2 & 0x1FFFFu) * 8 + c];
        q3.u = featq[(size_t)(pr3 & 0x1FFFFu) * 8 + c];
        int d0 = pr0 >> 17, d1 = pr1 >> 17, d2 = pr2 >> 17, d3 = pr3 >> 17;
#pragma unroll
        for (int j = 0; j < 8; j++) atomicAdd(&acc[d0 * 65 + c * 8 + j], (float)q0.h[j]);
#pragma unroll
        for (int j = 0; j < 8; j++) atomicAdd(&acc[d1 * 65 + c * 8 + j], (float)q1.h[j]);
#pragma unroll
        for (int j = 0; j < 8; j++) atomicAdd(&acc[d2 * 65 + c * 8 + j], (float)q2.h[j]);
#pragma unroll
        for (int j = 0; j < 8; j++) atomicAdd(&acc[d3 * 65 + c * 8 + j], (float)q3.h[j]);
        if (c == 0) {
            atomicAdd(&cnt[d0], 1); atomicAdd(&cnt[d1], 1);
            atomicAdd(&cnt[d2], 1); atomicAdd(&cnt[d3], 1);
        }
    }
    // drain: one group at a time, possibly partial
    for (; e < end; e += 64) {
        int m = end - e;  // >=1
        unsigned int pr = pairs[e + (g < m ? g : m - 1)];
        int srcn = pr & 0x1FFFFu;
        int dl = pr >> 17;
        H8U4 q;
        q.u = featq[(size_t)srcn * 8 + c];
        if (g < m) {
#pragma unroll
            for (int j = 0; j < 8; j++) atomicAdd(&acc[dl * 65 + c * 8 + j], (float)q.h[j]);
            if (c == 0) atomicAdd(&cnt[dl], 1);
        }
    }
    __syncthreads();

    // scale by 1/deg, convert to f16, coalesced write: flat uint4 index per thread
#pragma unroll
    for (int r = 0; r < 2; r++) {
        int flat = r * 512 + t;       // 0..1023 = 128 nodes * 8 chunks
        int n = flat >> 3, ch = flat & 7;
        int node = (b << SHIFT) + n;
        if (node < NN) {
            int dg = cnt[n];
            float s = (dg > 0) ? (1.0f / (float)dg) : 0.0f;
            H8U4 rr;
#pragma unroll
            for (int j = 0; j < 8; j++) rr.h[j] = (_Float16)(acc[n * 65 + ch * 8 + j] * s);
            outq[(size_t)node * 8 + ch] = rr.u;
        }
    }
}

// ---------------- MFMA dual GEMM: relu([agg|root] @ WcatT^T + b), optional @Wfc+bfc head ----------------
template <bool FUSE_HEAD>
__global__ __launch_bounds__(256) void k_linear(const uint4* __restrict__ aggq, const uint4* __restrict__ rootq,
                                                const uint4* __restrict__ wtq,   // WcatT f16 [64][128] as uint4
                                                const float* __restrict__ bias,
                                                const float* __restrict__ Wfc, const float* __restrict__ bfc,
                                                float* __restrict__ out_f32, unsigned short* __restrict__ out_f16) {
    int tid = threadIdx.x;
    int wave = tid >> 6, lane = tid & 63;
    int nb = blockIdx.x * 64 + wave * 16;
    int m = lane & 15, quad = lane >> 4;

    int an = nb + m;
    if (an > NN - 1) an = NN - 1;
    H8U4 a[4];
    a[0].u = aggq[(size_t)an * 8 + quad];
    a[1].u = aggq[(size_t)an * 8 + 4 + quad];
    a[2].u = rootq[(size_t)an * 8 + quad];
    a[3].u = rootq[(size_t)an * 8 + 4 + quad];

    f32x4 acc[4];
#pragma unroll
    for (int n = 0; n < 4; n++) acc[n] = (f32x4){0.f, 0.f, 0.f, 0.f};

#pragma unroll
    for (int ncol = 0; ncol < 4; ncol++) {
        int col = ncol * 16 + m;
#pragma unroll
        for (int ki = 0; ki < 4; ki++) {
            H8U4 b;
            b.u = wtq[col * 16 + ki * 4 + quad];
            acc[ncol] = __builtin_amdgcn_mfma_f32_16x16x32_f16(a[ki].h, b.h, acc[ncol], 0, 0, 0);
        }
    }

    float bs[4];
#pragma unroll
    for (int ncol = 0; ncol < 4; ncol++) bs[ncol] = bias[ncol * 16 + m];

    if (!FUSE_HEAD) {
#pragma unroll
        for (int r = 0; r < 4; r++) {
            int node = nb + quad * 4 + r;
            if (node < NN) {
#pragma unroll
                for (int ncol = 0; ncol < 4; ncol++) {
                    float v = fmaxf(acc[ncol][r] + bs[ncol], 0.f);
                    _Float16 hv = (_Float16)v;
                    out_f16[(size_t)node * 64 + ncol * 16 + m] = *(unsigned short*)&hv;
                }
            }
        }
    } else {
        float wf[4];
#pragma unroll
        for (int ncol = 0; ncol < 4; ncol++) wf[ncol] = Wfc[ncol * 16 + m];
#pragma unroll
        for (int r = 0; r < 4; r++) {
            int node = nb + quad * 4 + r;
            float partial = 0.f;
#pragma unroll
            for (int ncol = 0; ncol < 4; ncol++)
                partial += fmaxf(acc[ncol][r] + bs[ncol], 0.f) * wf[ncol];
            partial += __shfl_xor(partial, 1);
            partial += __shfl_xor(partial, 2);
            partial += __shfl_xor(partial, 4);
            partial += __shfl_xor(partial, 8);
            if (m == 0 && node < NN) out_f32[node] = partial + bfc[0];
        }
    }
}

extern "C" void kernel_launch(void* const* d_in, const int* in_sizes, int n_in,
                              void* d_out, int out_size, void* d_ws, size_t ws_size,
                              hipStream_t stream) {
    const float* x   = (const float*)d_in[0];
    const int*   ei  = (const int*)d_in[1];
    const float* Wl1 = (const float*)d_in[2];
    const float* bl1 = (const float*)d_in[3];
    const float* Wr1 = (const float*)d_in[4];
    const float* Wl2 = (const float*)d_in[5];
    const float* bl2 = (const float*)d_in[6];
    const float* Wr2 = (const float*)d_in[7];
    const float* Wfc = (const float*)d_in[8];
    const float* bfc = (const float*)d_in[9];
    float* out = (float*)d_out;

    const int* srcp = ei;       // edge_index[0]
    const int* dstp = ei + NE;  // edge_index[1]

    char* p = (char*)d_ws;
    auto carve = [&](size_t bytes) {
        char* q = p;
        p += (bytes + 255) & ~size_t(255);
        return q;
    };
    unsigned int*   pairs        = (unsigned int*)carve((size_t)NE * 4);      // persists (both layers)
    unsigned short* xh           = (unsigned short*)carve((size_t)NN * 64 * 2);
    unsigned short* h1h          = (unsigned short*)carve((size_t)NN * 64 * 2);
    unsigned short* aggh         = (unsigned short*)carve((size_t)NN * 64 * 2);
    unsigned short* wt1          = (unsigned short*)carve(64 * 128 * 2);
    unsigned short* wt2          = (unsigned short*)carve(64 * 128 * 2);
    int*            bin_total    = (int*)carve(NBUCK * 4);
    int*            bucket_start = (int*)carve((NBUCK + 1) * 4);              // persists (both layers)
    // hist (2.45 MB) aliases aggh (12.8 MB): dead after k_scatter, before layer-1 k_bucket_agg writes aggh
    int*            hist         = (int*)aggh;

    const int tile = (NN + 63) / 64;  // 1563

    // graph build + prep: 3 kernels + tiny memset. No node-level CSR needed --
    // aggregation consumes bucket-ordered pairs directly.
    hipMemsetAsync(bin_total, 0, NBUCK * 4, stream);
    k_hist<<<P1B, 256, 0, stream>>>((const float4*)x, (ushort4*)xh,
                                    Wl1, Wr1, wt1, Wl2, Wr2, wt2, dstp, hist, bin_total);
    k_cursor<<<NBUCK, 256, 0, stream>>>(hist, bin_total, bucket_start);
    k_scatter<<<P1B, 256, 0, stream>>>(srcp, dstp, hist, pairs);

    // layer 1: bucket gather-mean (fp32 LDS accum) -> aggh (f16), MFMA dual GEMM -> h1h (f16)
    k_bucket_agg<<<NBUCK, 512, 0, stream>>>((const uint4*)xh, pairs, bucket_start, (uint4*)aggh);
    k_linear<false><<<tile, 256, 0, stream>>>((const uint4*)aggh, (const uint4*)xh, (const uint4*)wt1,
                                              bl1, Wfc, bfc, nullptr, h1h);
    // layer 2 + fused head
    k_bucket_agg<<<NBUCK, 512, 0, stream>>>((const uint4*)h1h, pairs, bucket_start, (uint4*)aggh);
    k_linear<true><<<tile, 256, 0, stream>>>((const uint4*)aggh, (const uint4*)h1h, (const uint4*)wt2,
                                             bl2, Wfc, bfc, out, nullptr);
}

// Round 15
// 255.637 us; speedup vs baseline: 6.0155x; 6.0155x over previous
//
#include <hip/hip_runtime.h>
#include <hip/hip_fp16.h>

#define NN 100000
#define NE 1600000
#define SHIFT 8
#define NBUCK 391   // ceil(NN / 256) dst-buckets, 256 nodes each
#define P1B   391   // edge-slice blocks
#define EPB   4093  // ceil(NE / P1B)

typedef _Float16 f16x8 __attribute__((ext_vector_type(8)));
typedef float f32x4 __attribute__((ext_vector_type(4)));
union H8U4 { f16x8 h; uint4 u; };

// 256-thread inclusive Hillis-Steele scan in LDS; returns inclusive value for this thread.
__device__ __forceinline__ int scan256(int* s, int t, int v) {
    s[t] = v;
    __syncthreads();
    for (int off = 1; off < 256; off <<= 1) {
        int add = (t >= off) ? s[t - off] : 0;
        __syncthreads();
        s[t] += add;
        __syncthreads();
    }
    return s[t];
}

// ---------------- fused: f16 convert + weight prep + LDS histogram + bin totals ----------------
__global__ __launch_bounds__(256) void k_hist(
    const float4* __restrict__ x4, ushort4* __restrict__ xh4,
    const float* __restrict__ Wl1, const float* __restrict__ Wr1, unsigned short* __restrict__ wt1,
    const float* __restrict__ Wl2, const float* __restrict__ Wr2, unsigned short* __restrict__ wt2,
    const int* __restrict__ dst, int* __restrict__ hist, int* __restrict__ bin_total)
{
    __shared__ int h[NBUCK];
    int t = threadIdx.x, blk = blockIdx.x;

    const int n4 = NN * 16;
    const int per = (n4 + P1B - 1) / P1B;  // 4093
    int cb = blk * per, ce = min(cb + per, n4);
    for (int i = cb + t; i < ce; i += 256) {
        float4 f = x4[i];
        _Float16 a = (_Float16)f.x, b = (_Float16)f.y, c = (_Float16)f.z, d = (_Float16)f.w;
        ushort4 u;
        u.x = *(unsigned short*)&a; u.y = *(unsigned short*)&b;
        u.z = *(unsigned short*)&c; u.w = *(unsigned short*)&d;
        xh4[i] = u;
    }
    if (blk < 64) {  // blocks 0..31 -> wt1, 32..63 -> wt2
        int idx = (blk & 31) * 256 + t;  // 0..8191
        const float* Wl = (blk < 32) ? Wl1 : Wl2;
        const float* Wr = (blk < 32) ? Wr1 : Wr2;
        unsigned short* wt = (blk < 32) ? wt1 : wt2;
        int n = idx >> 7, k = idx & 127;
        float v = (k < 64) ? Wl[k * 64 + n] : Wr[(k - 64) * 64 + n];
        _Float16 hv = (_Float16)v;
        wt[idx] = *(unsigned short*)&hv;
    }

    for (int i = t; i < NBUCK; i += 256) h[i] = 0;
    __syncthreads();
    int eb = blk * EPB, ee = min(eb + EPB, NE);
    for (int e = eb + t; e < ee; e += 256) atomicAdd(&h[dst[e] >> SHIFT], 1);
    __syncthreads();
    for (int i = t; i < NBUCK; i += 256) {
        int v = h[i];
        hist[(size_t)i * P1B + blk] = v;
        if (v) atomicAdd(&bin_total[i], v);  // fire-and-forget, no return dependency
    }
}

// ---------------- cursor bases: block b computes bucket_start[b] locally, then scans hist row b ----------------
__global__ __launch_bounds__(256) void k_cursor(int* __restrict__ hist, const int* __restrict__ bin_total,
                                                int* __restrict__ bucket_start, int* __restrict__ offsets) {
    __shared__ int sS[256];
    int b = blockIdx.x, t = threadIdx.x;

    // base = sum of bin_total[0..b-1]
    int v = 0;
    for (int i = t; i < b; i += 256) v += bin_total[i];
    sS[t] = v;
    __syncthreads();
    for (int s = 128; s > 0; s >>= 1) {
        if (t < s) sS[t] += sS[t + s];
        __syncthreads();
    }
    int base = sS[0];
    __syncthreads();
    if (t == 0) bucket_start[b] = base;
    if (b == 0 && t == 0) { bucket_start[NBUCK] = NE; offsets[NN] = NE; }

    // exclusive scan of hist row b (length P1B=391, 2 chunks of 256), in place, +base
    int carry = 0;
#pragma unroll
    for (int c = 0; c < 2; c++) {
        int idx = c * 256 + t;
        int hv = (idx < P1B) ? hist[(size_t)b * P1B + idx] : 0;
        int incl = scan256(sS, t, hv);
        if (idx < P1B) hist[(size_t)b * P1B + idx] = base + carry + incl - hv;
        __syncthreads();
        carry += sS[255];
        __syncthreads();
    }
}

// ---------------- scatter packed (src | (dst&255)<<17) into bucket order ----------------
__global__ __launch_bounds__(256) void k_scatter(const int* __restrict__ src, const int* __restrict__ dst,
                                                 const int* __restrict__ hist, unsigned int* __restrict__ pairs) {
    __shared__ int cur[NBUCK];
    int t = threadIdx.x, blk = blockIdx.x;
    for (int i = t; i < NBUCK; i += 256) cur[i] = hist[(size_t)i * P1B + blk];
    __syncthreads();
    int eb = blk * EPB, ee = min(eb + EPB, NE);
    for (int e = eb + t; e < ee; e += 256) {
        int d = dst[e];
        int pos = atomicAdd(&cur[d >> SHIFT], 1);
        pairs[pos] = (unsigned int)src[e] | ((unsigned int)(d & 255) << 17);
    }
}

// ---------------- per-bucket CSR finalize: 256 nodes/bucket ----------------
__global__ __launch_bounds__(256) void k_bucket_csr(const unsigned int* __restrict__ pairs,
                                                    const int* __restrict__ bucket_start,
                                                    int* __restrict__ ssrc, int* __restrict__ offsets,
                                                    float* __restrict__ inv_deg) {
    __shared__ int cnt[256];
    __shared__ int sS[256];
    int b = blockIdx.x, t = threadIdx.x;
    cnt[t] = 0;
    __syncthreads();
    int beg = bucket_start[b], end = bucket_start[b + 1];
    for (int e = beg + t; e < end; e += 256) atomicAdd(&cnt[pairs[e] >> 17], 1);
    __syncthreads();
    int deg = cnt[t];
    int incl = scan256(sS, t, deg);
    int ex = incl - deg;
    int node = (b << SHIFT) + t;
    if (node < NN) {
        offsets[node] = beg + ex;
        inv_deg[node] = (deg > 0) ? (1.0f / (float)deg) : 0.0f;
    }
    __syncthreads();
    cnt[t] = beg + ex;  // cursor
    __syncthreads();
    for (int e = beg + t; e < end; e += 256) {
        unsigned int pr = pairs[e];
        int pos = atomicAdd(&cnt[pr >> 17], 1);
        ssrc[pos] = (int)(pr & 0x1FFFFu);
    }
}

// ---------------- mean aggregation: TWO nodes per wave, interleaved gathers (4 in flight) ----------------
// Lane l: chunk c=l&7 (16B of f16x8), edge-slot g=l>>3 (8 slots shared by both nodes).
__global__ __launch_bounds__(256) void k_aggregate(const uint4* __restrict__ featq,
                                                   const int* __restrict__ ssrc,
                                                   const int* __restrict__ offsets, const float* __restrict__ inv_deg,
                                                   uint4* __restrict__ outq) {
    int pairid = blockIdx.x * 4 + (threadIdx.x >> 6);
    int node0 = pairid * 2;
    if (node0 >= NN) return;
    int node1 = node0 + 1;
    bool has1 = node1 < NN;
    int lane = threadIdx.x & 63;
    int c = lane & 7, g = lane >> 3;

    int beg0 = offsets[node0], end0 = offsets[node0 + 1];
    int beg1 = has1 ? offsets[node1] : 0, end1 = has1 ? offsets[node1 + 1] : 0;
    H8U4 acc0, acc1;
    acc0.h = (f16x8)(_Float16)0;
    acc1.h = (f16x8)(_Float16)0;
    int e0 = beg0, e1 = beg1;

    // joint main loop: 16 edges per node per iter -> 4 independent feature gathers in flight
    while (e0 + 16 <= end0 && e1 + 16 <= end1) {
        int i00 = ssrc[e0 + g], i01 = ssrc[e0 + 8 + g];
        int i10 = ssrc[e1 + g], i11 = ssrc[e1 + 8 + g];
        H8U4 q00, q01, q10, q11;
        q00.u = featq[(size_t)i00 * 8 + c];
        q01.u = featq[(size_t)i01 * 8 + c];
        q10.u = featq[(size_t)i10 * 8 + c];
        q11.u = featq[(size_t)i11 * 8 + c];
        acc0.h += q00.h; acc0.h += q01.h;
        acc1.h += q10.h; acc1.h += q11.h;
        e0 += 16; e1 += 16;
    }
    // drain node0
    for (; e0 + 16 <= end0; e0 += 16) {
        int i0 = ssrc[e0 + g], i1 = ssrc[e0 + 8 + g];
        H8U4 q0, q1;
        q0.u = featq[(size_t)i0 * 8 + c];
        q1.u = featq[(size_t)i1 * 8 + c];
        acc0.h += q0.h; acc0.h += q1.h;
    }
    for (; e0 < end0; e0 += 8) {
        int m = end0 - e0;
        int idx = ssrc[e0 + (g < m ? g : m - 1)];
        H8U4 q;
        q.u = featq[(size_t)idx * 8 + c];
        if (g < m) acc0.h += q.h;
    }
    // drain node1
    for (; e1 + 16 <= end1; e1 += 16) {
        int i0 = ssrc[e1 + g], i1 = ssrc[e1 + 8 + g];
        H8U4 q0, q1;
        q0.u = featq[(size_t)i0 * 8 + c];
        q1.u = featq[(size_t)i1 * 8 + c];
        acc1.h += q0.h; acc1.h += q1.h;
    }
    for (; e1 < end1; e1 += 8) {
        int m = end1 - e1;
        int idx = ssrc[e1 + (g < m ? g : m - 1)];
        H8U4 q;
        q.u = featq[(size_t)idx * 8 + c];
        if (g < m) acc1.h += q.h;
    }

    // fold 8 edge-slots (lanes differing in bits 3..5), both accumulators
#pragma unroll
    for (int mask = 8; mask <= 32; mask <<= 1) {
        H8U4 o0, o1;
        o0.u.x = __shfl_xor(acc0.u.x, mask); o0.u.y = __shfl_xor(acc0.u.y, mask);
        o0.u.z = __shfl_xor(acc0.u.z, mask); o0.u.w = __shfl_xor(acc0.u.w, mask);
        o1.u.x = __shfl_xor(acc1.u.x, mask); o1.u.y = __shfl_xor(acc1.u.y, mask);
        o1.u.z = __shfl_xor(acc1.u.z, mask); o1.u.w = __shfl_xor(acc1.u.w, mask);
        acc0.h += o0.h;
        acc1.h += o1.h;
    }

    if (g == 0) {
        float s0 = inv_deg[node0];
        H8U4 r;
#pragma unroll
        for (int j = 0; j < 8; j++) r.h[j] = (_Float16)((float)acc0.h[j] * s0);
        outq[(size_t)node0 * 8 + c] = r.u;
        if (has1) {
            float s1 = inv_deg[node1];
#pragma unroll
            for (int j = 0; j < 8; j++) r.h[j] = (_Float16)((float)acc1.h[j] * s1);
            outq[(size_t)node1 * 8 + c] = r.u;
        }
    }
}

// ---------------- MFMA dual GEMM: relu([agg|root] @ WcatT^T + b), optional @Wfc+bfc head ----------------
template <bool FUSE_HEAD>
__global__ __launch_bounds__(256) void k_linear(const uint4* __restrict__ aggq, const uint4* __restrict__ rootq,
                                                const uint4* __restrict__ wtq,   // WcatT f16 [64][128] as uint4
                                                const float* __restrict__ bias,
                                                const float* __restrict__ Wfc, const float* __restrict__ bfc,
                                                float* __restrict__ out_f32, unsigned short* __restrict__ out_f16) {
    int tid = threadIdx.x;
    int wave = tid >> 6, lane = tid & 63;
    int nb = blockIdx.x * 64 + wave * 16;
    int m = lane & 15, quad = lane >> 4;

    int an = nb + m;
    if (an > NN - 1) an = NN - 1;
    H8U4 a[4];
    a[0].u = aggq[(size_t)an * 8 + quad];
    a[1].u = aggq[(size_t)an * 8 + 4 + quad];
    a[2].u = rootq[(size_t)an * 8 + quad];
    a[3].u = rootq[(size_t)an * 8 + 4 + quad];

    f32x4 acc[4];
#pragma unroll
    for (int n = 0; n < 4; n++) acc[n] = (f32x4){0.f, 0.f, 0.f, 0.f};

#pragma unroll
    for (int ncol = 0; ncol < 4; ncol++) {
        int col = ncol * 16 + m;
#pragma unroll
        for (int ki = 0; ki < 4; ki++) {
            H8U4 b;
            b.u = wtq[col * 16 + ki * 4 + quad];
            acc[ncol] = __builtin_amdgcn_mfma_f32_16x16x32_f16(a[ki].h, b.h, acc[ncol], 0, 0, 0);
        }
    }

    float bs[4];
#pragma unroll
    for (int ncol = 0; ncol < 4; ncol++) bs[ncol] = bias[ncol * 16 + m];

    if (!FUSE_HEAD) {
#pragma unroll
        for (int r = 0; r < 4; r++) {
            int node = nb + quad * 4 + r;
            if (node < NN) {
#pragma unroll
                for (int ncol = 0; ncol < 4; ncol++) {
                    float v = fmaxf(acc[ncol][r] + bs[ncol], 0.f);
                    _Float16 hv = (_Float16)v;
                    out_f16[(size_t)node * 64 + ncol * 16 + m] = *(unsigned short*)&hv;
                }
            }
        }
    } else {
        float wf[4];
#pragma unroll
        for (int ncol = 0; ncol < 4; ncol++) wf[ncol] = Wfc[ncol * 16 + m];
#pragma unroll
        for (int r = 0; r < 4; r++) {
            int node = nb + quad * 4 + r;
            float partial = 0.f;
#pragma unroll
            for (int ncol = 0; ncol < 4; ncol++)
                partial += fmaxf(acc[ncol][r] + bs[ncol], 0.f) * wf[ncol];
            partial += __shfl_xor(partial, 1);
            partial += __shfl_xor(partial, 2);
            partial += __shfl_xor(partial, 4);
            partial += __shfl_xor(partial, 8);
            if (m == 0 && node < NN) out_f32[node] = partial + bfc[0];
        }
    }
}

extern "C" void kernel_launch(void* const* d_in, const int* in_sizes, int n_in,
                              void* d_out, int out_size, void* d_ws, size_t ws_size,
                              hipStream_t stream) {
    const float* x   = (const float*)d_in[0];
    const int*   ei  = (const int*)d_in[1];
    const float* Wl1 = (const float*)d_in[2];
    const float* bl1 = (const float*)d_in[3];
    const float* Wr1 = (const float*)d_in[4];
    const float* Wl2 = (const float*)d_in[5];
    const float* bl2 = (const float*)d_in[6];
    const float* Wr2 = (const float*)d_in[7];
    const float* Wfc = (const float*)d_in[8];
    const float* bfc = (const float*)d_in[9];
    float* out = (float*)d_out;

    const int* srcp = ei;       // edge_index[0]
    const int* dstp = ei + NE;  // edge_index[1]

    char* p = (char*)d_ws;
    auto carve = [&](size_t bytes) {
        char* q = p;
        p += (bytes + 255) & ~size_t(255);
        return q;
    };
    int*            offsets = (int*)carve((size_t)(NN + 1) * 4);
    float*          inv_deg = (float*)carve((size_t)NN * 4);
    int*            ssrc    = (int*)carve((size_t)NE * 4);
    unsigned short* xh      = (unsigned short*)carve((size_t)NN * 64 * 2);
    unsigned short* h1h     = (unsigned short*)carve((size_t)NN * 64 * 2);
    unsigned short* aggh    = (unsigned short*)carve((size_t)NN * 64 * 2);
    unsigned short* wt1     = (unsigned short*)carve(64 * 128 * 2);
    unsigned short* wt2     = (unsigned short*)carve(64 * 128 * 2);
    // graph-build temporaries alias onto aggh (dead before k_aggregate first writes aggh):
    // pairs 6.4 MB + hist 611 KB + bin_total/bucket_start ~3 KB < 12.8 MB
    unsigned int* pairs        = (unsigned int*)aggh;
    int*          hist         = (int*)(pairs + NE);
    int*          bin_total    = hist + (size_t)NBUCK * P1B;
    int*          bucket_start = bin_total + NBUCK;  // NBUCK+1 ints

    const int tile = (NN + 63) / 64;  // 1563

    // graph build + prep: 4 launches + tiny memset (kernel boundary = cheap grid barrier;
    // coop grid.sync measured ~35us/sync on MI355X in R11; LDS-atomic scatter-accumulate
    // measured 20x slower than CSR+register accumulation in R14)
    hipMemsetAsync(bin_total, 0, NBUCK * 4, stream);
    k_hist<<<P1B, 256, 0, stream>>>((const float4*)x, (ushort4*)xh,
                                    Wl1, Wr1, wt1, Wl2, Wr2, wt2, dstp, hist, bin_total);
    k_cursor<<<NBUCK, 256, 0, stream>>>(hist, bin_total, bucket_start, offsets);
    k_scatter<<<P1B, 256, 0, stream>>>(srcp, dstp, hist, pairs);
    k_bucket_csr<<<NBUCK, 256, 0, stream>>>(pairs, bucket_start, ssrc, offsets, inv_deg);

    // layer 1: gather f16 x -> aggh (f16), MFMA dual GEMM -> h1h (f16)
    const int aggblocks = ((NN + 1) / 2 + 3) / 4;  // 2 nodes per wave, 4 waves per block
    k_aggregate<<<aggblocks, 256, 0, stream>>>((const uint4*)xh, ssrc, offsets, inv_deg, (uint4*)aggh);
    k_linear<false><<<tile, 256, 0, stream>>>((const uint4*)aggh, (const uint4*)xh, (const uint4*)wt1,
                                              bl1, Wfc, bfc, nullptr, h1h);
    // layer 2 + fused head
    k_aggregate<<<aggblocks, 256, 0, stream>>>((const uint4*)h1h, ssrc, offsets, inv_deg, (uint4*)aggh);
    k_linear<true><<<tile, 256, 0, stream>>>((const uint4*)aggh, (const uint4*)h1h, (const uint4*)wt2,
                                             bl2, Wfc, bfc, out, nullptr);
}